// Round 10
// baseline (1360.580 us; speedup 1.0000x reference)
//
#include <hip/hip_runtime.h>
#include <cstdint>

#define NOUTC 131072
#define NINC  16384
#define CAP   204800        // sparse entry capacity (expected ~156K)
#define NCH   128           // chunks of 1024 rows
#define MAXB  3328          // phase1 grid (>= CAP/64)

using uint = unsigned int;

__device__ __forceinline__ uint fkey(float v){
  uint u = __float_as_uint(v);
  return (u & 0x80000000u) ? ~u : (u | 0x80000000u);
}

// tap index for output-child o gathering sibling q (d = q - o per dim)
__device__ __forceinline__ int ktap(int o, int q){
  int d0 = ((q>>2)&1) - ((o>>2)&1);
  int d1 = ((q>>1)&1) - ((o>>1)&1);
  int d2 = (q&1) - (o&1);
  return (d0+1)*9 + (d1+1)*3 + (d2+1);
}
// is tap k a guaranteed-sibling tap for child o?
__device__ __forceinline__ bool is_sib(int o, int k){
  int k0 = k/9, k1 = (k%9)/3, k2 = k%3;
  int q0 = ((o>>2)&1) + k0 - 1;
  int q1 = ((o>>1)&1) + k1 - 1;
  int q2 = (o&1)      + k2 - 1;
  return (q0>=0 && q0<=1 && q1>=0 && q1<=1 && q2>=0 && q2<=1);
}

// ---------------------------------------------------------------------------
// WW expansion preps
// ---------------------------------------------------------------------------
__global__ __launch_bounds__(256)
void ww_prep_c0(const float* __restrict__ Wc0, float* __restrict__ WW)
{
  int tid = blockIdx.x * 256 + threadIdx.x;   // < 262144
  int col = tid & 511, rowk = tid >> 9;
  int o = col >> 6, co = col & 63;
  int q = rowk >> 6, ci = rowk & 63;
  WW[tid] = Wc0[ktap(o, q) * 4096 + ci * 64 + co];
}

// WW2 [512][256]: cols 0..127 = W00 sib expansion; cols 128..255 = blockdiag W10
__global__ __launch_bounds__(256)
void ww_prep_a2(const float* __restrict__ W00i, const float* __restrict__ W10i,
                float* __restrict__ WW2)
{
  int tid = blockIdx.x * 256 + threadIdx.x;   // < 131072
  int col = tid & 255, rowk = tid >> 8;
  int q = rowk >> 6, ci = rowk & 63;
  float v;
  if (col < 128){
    int o = col >> 4, co = col & 15;
    v = W00i[ktap(o, q) * 1024 + ci * 16 + co];
  } else {
    int c2 = col - 128;
    int o = c2 >> 4, co = c2 & 15;
    v = (q == o) ? W10i[ci * 16 + co] : 0.f;
  }
  WW2[tid] = v;
}

// ---------------------------------------------------------------------------
// gemm_ww3: C[16384][N] = A[16384][512] @ B[512][N] (+bias). TM=TN=8,
// BLKM=BLKN=128, 1.0 B/FMA. All LDS accesses conflict-free:
//  - As reads: 4-address broadcast per wave (free)
//  - Bs column-pair swizzle (slot = ((c&1)<<4)|(c>>1)): reads are 16
//    consecutive float4s (2-way = free); staging writes contiguous.
// DUAL: cols<128 -> C (t0, no relu); cols>=128 -> C2 (t1, relu).
// ---------------------------------------------------------------------------
template<int BMASK, bool DUAL>
__global__ __launch_bounds__(256)
void gemm_ww3(const float* __restrict__ A, const float* __restrict__ Bw,
              const float* __restrict__ bias, const float* __restrict__ bias2,
              float* __restrict__ C, float* __restrict__ C2, int N)
{
  __shared__ float As[32 * 132];
  __shared__ float Bs[32 * 132];

  const int t  = threadIdx.x;
  const int mb = blockIdx.x & 127;
  const int nb = blockIdx.x >> 7;
  const int mg = t >> 4, ng = t & 15;

  float4 ast[4], bst[4];
  float acc[8][8];
  #pragma unroll
  for (int a = 0; a < 8; ++a)
    #pragma unroll
    for (int b = 0; b < 8; ++b) acc[a][b] = 0.f;

  auto load_a = [&](int kc){
    #pragma unroll
    for (int i2 = 0; i2 < 4; ++i2){
      int idx = t + i2 * 256;
      int row = idx >> 3, c4 = idx & 7;
      ast[i2] = *reinterpret_cast<const float4*>(
          A + (size_t)(mb * 128 + row) * 512 + kc * 32 + c4 * 4);
    }
  };
  auto load_b = [&](int kc){
    #pragma unroll
    for (int i2 = 0; i2 < 4; ++i2){
      int idx = t + i2 * 256;
      int kk = idx >> 5, c4 = idx & 31;
      bst[i2] = *reinterpret_cast<const float4*>(
          Bw + (size_t)(kc * 32 + kk) * N + nb * 128 + c4 * 4);
    }
  };

  load_a(0); load_b(0);

  for (int kc = 0; kc < 16; ++kc){
    #pragma unroll
    for (int i2 = 0; i2 < 4; ++i2){
      int idx = t + i2 * 256;
      int row = idx >> 3, c4 = idx & 7;
      As[(c4*4+0)*132 + row] = ast[i2].x;
      As[(c4*4+1)*132 + row] = ast[i2].y;
      As[(c4*4+2)*132 + row] = ast[i2].z;
      As[(c4*4+3)*132 + row] = ast[i2].w;
    }
    #pragma unroll
    for (int i2 = 0; i2 < 4; ++i2){
      int idx = t + i2 * 256;
      int kk = idx >> 5, c4 = idx & 31;
      int slot = ((c4 & 1) << 4) | (c4 >> 1);
      *reinterpret_cast<float4*>(&Bs[kk * 132 + slot * 4]) = bst[i2];
    }
    __syncthreads();
    if (kc < 15){ load_a(kc + 1); load_b(kc + 1); }
    #pragma unroll 4
    for (int kk = 0; kk < 32; ++kk){
      float4 a0 = *reinterpret_cast<const float4*>(&As[kk*132 + mg*8]);
      float4 a1 = *reinterpret_cast<const float4*>(&As[kk*132 + mg*8 + 4]);
      float av[8] = {a0.x,a0.y,a0.z,a0.w, a1.x,a1.y,a1.z,a1.w};
      float4 b0 = *reinterpret_cast<const float4*>(&Bs[kk*132 + ng*4]);
      float4 b1 = *reinterpret_cast<const float4*>(&Bs[kk*132 + 64 + ng*4]);
      float bv[8] = {b0.x,b0.y,b0.z,b0.w, b1.x,b1.y,b1.z,b1.w};
      #pragma unroll
      for (int a = 0; a < 8; ++a)
        #pragma unroll
        for (int b = 0; b < 8; ++b)
          acc[a][b] = fmaf(av[a], bv[b], acc[a][b]);
    }
    __syncthreads();
  }

  const int colbase = nb * 128 + ng * 8;
  if (!DUAL || colbase < 128){
    const int stride = DUAL ? 128 : N;
    float bv[8];
    #pragma unroll
    for (int b = 0; b < 8; ++b) bv[b] = bias[(colbase + b) & BMASK];
    #pragma unroll
    for (int a = 0; a < 8; ++a){
      int row = mb * 128 + mg * 8 + a;
      float* dst = C + (size_t)row * stride + colbase;
      float4 o0 = {acc[a][0]+bv[0], acc[a][1]+bv[1], acc[a][2]+bv[2], acc[a][3]+bv[3]};
      float4 o1 = {acc[a][4]+bv[4], acc[a][5]+bv[5], acc[a][6]+bv[6], acc[a][7]+bv[7]};
      *reinterpret_cast<float4*>(dst)     = o0;
      *reinterpret_cast<float4*>(dst + 4) = o1;
    }
  } else {
    const int cb2 = colbase - 128;
    float bv[8];
    #pragma unroll
    for (int b = 0; b < 8; ++b) bv[b] = bias2[(cb2 + b) & 15];
    #pragma unroll
    for (int a = 0; a < 8; ++a){
      int row = mb * 128 + mg * 8 + a;
      float o[8];
      #pragma unroll
      for (int b = 0; b < 8; ++b){
        float v = acc[a][b] + bv[b];
        o[b] = v > 0.f ? v : 0.f;
      }
      float* dst = C2 + (size_t)row * 128 + cb2;
      float4 o0 = {o[0], o[1], o[2], o[3]};
      float4 o1 = {o[4], o[5], o[6], o[7]};
      *reinterpret_cast<float4*>(dst)     = o0;
      *reinterpret_cast<float4*>(dst + 4) = o1;
    }
  }
}

// ---------------------------------------------------------------------------
// Sparse-entry list build: count -> scan -> fill (stable order => deterministic)
// ---------------------------------------------------------------------------
__global__ __launch_bounds__(256)
void count_kernel(const int* __restrict__ nbr, uint* __restrict__ counts)
{
  int k = blockIdx.x / NCH, cb = blockIdx.x % NCH;
  int t = threadIdx.x;
  int cnt = 0;
  for (int s = 0; s < 4; ++s){
    int row = cb*1024 + s*256 + t;
    int idx = nbr[(size_t)k*NOUTC + row];
    bool f = (idx != NOUTC) && !is_sib(row & 7, k);
    cnt += __syncthreads_count(f);
  }
  if (t == 0) counts[blockIdx.x] = (uint)cnt;
}

__global__ __launch_bounds__(256)
void scan_kernel(const uint* __restrict__ counts, uint* __restrict__ choff,
                 int* __restrict__ karr)
{
  __shared__ uint kt[27], segs[27], sege[27];
  int t = threadIdx.x;
  if (t < 27){ uint s = 0; for (int cb = 0; cb < NCH; ++cb) s += counts[t*NCH+cb]; kt[t] = s; }
  __syncthreads();
  if (t == 0){
    uint run = 0;
    for (int k = 0; k < 27; ++k){
      segs[k] = run;
      uint pad = (kt[k] + 63u) & ~63u;
      if (run + pad > CAP) pad = (run < CAP) ? ((CAP - run) & ~63u) : 0;
      run += pad;
      sege[k] = run;
    }
  }
  __syncthreads();
  if (t < 27){
    uint run = segs[t];
    for (int cb = 0; cb < NCH; ++cb){ choff[t*NCH+cb] = run; run += counts[t*NCH+cb]; }
  }
  __syncthreads();
  for (int b = t; b < MAXB; b += 256){
    int kk = -1; uint e = (uint)b * 64u;
    for (int k = 0; k < 27; ++k) if (e >= segs[k] && e < sege[k]) kk = k;
    karr[b] = kk;
  }
}

__global__ __launch_bounds__(256)
void fill_kernel(const int* __restrict__ nbr, const uint* __restrict__ choff,
                 uint2* __restrict__ entries)
{
  __shared__ uint wc[4][4];
  __shared__ uint sbase[4];
  int k = blockIdx.x / NCH, cb = blockIdx.x % NCH;
  int t = threadIdx.x, w = t >> 6, l = t & 63;
  uint base = choff[blockIdx.x];
  int rows[4], idxs[4];
  unsigned long long bal[4];
  for (int s = 0; s < 4; ++s){
    int row = cb*1024 + s*256 + t;
    int idx = nbr[(size_t)k*NOUTC + row];
    bool f = (idx != NOUTC) && !is_sib(row & 7, k);
    bal[s] = __ballot(f);
    if (l == 0) wc[s][w] = (uint)__popcll(bal[s]);
    rows[s] = row; idxs[s] = idx;
  }
  __syncthreads();
  if (t == 0){
    uint r = 0;
    for (int s = 0; s < 4; ++s){ sbase[s] = r; for (int w2 = 0; w2 < 4; ++w2) r += wc[s][w2]; }
  }
  __syncthreads();
  for (int s = 0; s < 4; ++s){
    if ((bal[s] >> l) & 1ull){
      uint off = sbase[s];
      for (int w2 = 0; w2 < w; ++w2) off += wc[s][w2];
      off += (uint)__popcll(bal[s] & ((1ull << l) - 1ull));
      uint pos = base + off;
      if (pos < CAP) entries[pos] = make_uint2((uint)rows[s], (uint)idxs[s]);
    }
  }
}

// ---------------------------------------------------------------------------
// Sparse phase1: 64 entries/block dense GEMM into slab (global slot = b*64+e)
// ---------------------------------------------------------------------------
__global__ __launch_bounds__(128)
void p1c0_kernel(const float* __restrict__ feats, const float* __restrict__ Wc0,
                 const uint2* __restrict__ entries, const int* __restrict__ karr,
                 float* __restrict__ slab, int h)
{
  __shared__ float ft2[64*68];
  __shared__ float wbs[64*36];
  int b = blockIdx.x;
  int k = karr[b];
  if (k < 0) return;
  int t = threadIdx.x;
  for (int e = t; e < 512; e += 128){
    int ci = e >> 3, c4 = e & 7;
    float4 v = *reinterpret_cast<const float4*>(Wc0 + (size_t)k*4096 + ci*64 + h*32 + c4*4);
    *reinterpret_cast<float4*>(&wbs[ci*36 + c4*4]) = v;
  }
  {
    int e = t >> 1, part = t & 1;
    uint2 en = entries[(size_t)b*64 + e];
    int gidx = (en.x == 0xFFFFFFFFu) ? NOUTC : (int)en.y;
    const float4* src = reinterpret_cast<const float4*>(feats + (size_t)gidx*64 + part*32);
    #pragma unroll
    for (int j = 0; j < 8; ++j){
      float4 v = src[j];
      int ci = part*32 + j*4;
      ft2[(ci+0)*68 + e] = v.x; ft2[(ci+1)*68 + e] = v.y;
      ft2[(ci+2)*68 + e] = v.z; ft2[(ci+3)*68 + e] = v.w;
    }
  }
  __syncthreads();
  int sp = t & 1, tile = t >> 1, eg = tile >> 3, cg = tile & 7;
  float acc[8][4];
  #pragma unroll
  for (int a = 0; a < 8; ++a){ acc[a][0]=0.f; acc[a][1]=0.f; acc[a][2]=0.f; acc[a][3]=0.f; }
  for (int i = 0; i < 32; ++i){
    int ci = sp + 2*i;
    float4 f0 = *reinterpret_cast<const float4*>(&ft2[ci*68 + eg*8]);
    float4 f1 = *reinterpret_cast<const float4*>(&ft2[ci*68 + eg*8 + 4]);
    float fv[8] = {f0.x,f0.y,f0.z,f0.w, f1.x,f1.y,f1.z,f1.w};
    float4 wv = *reinterpret_cast<const float4*>(&wbs[ci*36 + cg*4]);
    float wa[4] = {wv.x, wv.y, wv.z, wv.w};
    #pragma unroll
    for (int a = 0; a < 8; ++a)
      #pragma unroll
      for (int j = 0; j < 4; ++j)
        acc[a][j] = fmaf(fv[a], wa[j], acc[a][j]);
  }
  #pragma unroll
  for (int a = 0; a < 8; ++a)
    #pragma unroll
    for (int j = 0; j < 4; ++j) acc[a][j] += __shfl_xor(acc[a][j], 1, 64);
  if (sp == 0){
    #pragma unroll
    for (int a = 0; a < 8; ++a){
      int e = eg*8 + a;
      float4 v = {acc[a][0], acc[a][1], acc[a][2], acc[a][3]};
      *reinterpret_cast<float4*>(&slab[((size_t)b*64 + e)*32 + cg*4]) = v;
    }
  }
}

__global__ __launch_bounds__(128)
void p1a_kernel(const float* __restrict__ feats, const float* __restrict__ W00i,
                const uint2* __restrict__ entries, const int* __restrict__ karr,
                float* __restrict__ slab)
{
  __shared__ float ft2[64*68];
  __shared__ float wbs[64*18];
  int b = blockIdx.x;
  int k = karr[b];
  if (k < 0) return;
  int t = threadIdx.x;
  for (int e = t; e < 256; e += 128){
    int ci = e >> 2, c4 = e & 3;
    float4 v = *reinterpret_cast<const float4*>(W00i + (size_t)k*1024 + ci*16 + c4*4);
    *reinterpret_cast<float4*>(&wbs[ci*18 + c4*4]) = v;
  }
  {
    int e = t >> 1, part = t & 1;
    uint2 en = entries[(size_t)b*64 + e];
    int gidx = (en.x == 0xFFFFFFFFu) ? NOUTC : (int)en.y;
    const float4* src = reinterpret_cast<const float4*>(feats + (size_t)gidx*64 + part*32);
    #pragma unroll
    for (int j = 0; j < 8; ++j){
      float4 v = src[j];
      int ci = part*32 + j*4;
      ft2[(ci+0)*68 + e] = v.x; ft2[(ci+1)*68 + e] = v.y;
      ft2[(ci+2)*68 + e] = v.z; ft2[(ci+3)*68 + e] = v.w;
    }
  }
  __syncthreads();
  int sp = t & 1, tile = t >> 1, eg = tile >> 2, cg = tile & 3;
  float acc[4][4];
  #pragma unroll
  for (int a = 0; a < 4; ++a){ acc[a][0]=0.f; acc[a][1]=0.f; acc[a][2]=0.f; acc[a][3]=0.f; }
  for (int i = 0; i < 32; ++i){
    int ci = sp + 2*i;
    float4 f0 = *reinterpret_cast<const float4*>(&ft2[ci*68 + eg*4]);
    float fv[4] = {f0.x, f0.y, f0.z, f0.w};
    float4 wv = *reinterpret_cast<const float4*>(&wbs[ci*18 + cg*4]);
    float wa[4] = {wv.x, wv.y, wv.z, wv.w};
    #pragma unroll
    for (int a = 0; a < 4; ++a)
      #pragma unroll
      for (int j = 0; j < 4; ++j)
        acc[a][j] = fmaf(fv[a], wa[j], acc[a][j]);
  }
  #pragma unroll
  for (int a = 0; a < 4; ++a)
    #pragma unroll
    for (int j = 0; j < 4; ++j) acc[a][j] += __shfl_xor(acc[a][j], 1, 64);
  if (sp == 0){
    #pragma unroll
    for (int a = 0; a < 4; ++a){
      int e = eg*4 + a;
      float4 v = {acc[a][0], acc[a][1], acc[a][2], acc[a][3]};
      *reinterpret_cast<float4*>(&slab[((size_t)b*64 + e)*16 + cg*4]) = v;
    }
  }
}

// ---------------------------------------------------------------------------
// Combine: per-row exclusive; recomputes fill's stable ranks; adds slab; relu.
// ---------------------------------------------------------------------------
__global__ __launch_bounds__(256)
void cmbc0_kernel(const int* __restrict__ nbr, const uint* __restrict__ choff,
                  const float* __restrict__ slab, float* __restrict__ fb, int h)
{
  __shared__ uint wc[4][4];
  int cb = blockIdx.x >> 1, cq = blockIdx.x & 1;
  int t = threadIdx.x, w = t >> 6, l = t & 63;
  int co0 = h*32 + cq*16;
  float acc[4][16];
  #pragma unroll
  for (int s = 0; s < 4; ++s)
    #pragma unroll
    for (int j = 0; j < 16; ++j) acc[s][j] = 0.f;

  for (int k = 0; k < 27; ++k){
    unsigned long long bal[4];
    for (int s = 0; s < 4; ++s){
      int row = cb*1024 + s*256 + t;
      int idx = nbr[(size_t)k*NOUTC + row];
      bool f = (idx != NOUTC) && !is_sib(row & 7, k);
      bal[s] = __ballot(f);
      if (l == 0) wc[s][w] = (uint)__popcll(bal[s]);
    }
    __syncthreads();
    uint sbs[4];
    { uint r = 0; for (int s = 0; s < 4; ++s){ sbs[s] = r; for (int w2 = 0; w2 < 4; ++w2) r += wc[s][w2]; } }
    uint base = choff[k*NCH + cb];
    for (int s = 0; s < 4; ++s){
      if ((bal[s] >> l) & 1ull){
        uint off = sbs[s];
        for (int w2 = 0; w2 < w; ++w2) off += wc[s][w2];
        off += (uint)__popcll(bal[s] & ((1ull << l) - 1ull));
        uint pos = base + off;
        if (pos < CAP){
          const float4* sr = reinterpret_cast<const float4*>(slab + (size_t)pos*32 + cq*16);
          float4 a0 = sr[0], a1 = sr[1], a2 = sr[2], a3 = sr[3];
          acc[s][0]+=a0.x; acc[s][1]+=a0.y; acc[s][2]+=a0.z; acc[s][3]+=a0.w;
          acc[s][4]+=a1.x; acc[s][5]+=a1.y; acc[s][6]+=a1.z; acc[s][7]+=a1.w;
          acc[s][8]+=a2.x; acc[s][9]+=a2.y; acc[s][10]+=a2.z; acc[s][11]+=a2.w;
          acc[s][12]+=a3.x; acc[s][13]+=a3.y; acc[s][14]+=a3.z; acc[s][15]+=a3.w;
        }
      }
    }
    __syncthreads();
  }
  for (int s = 0; s < 4; ++s){
    int row = cb*1024 + s*256 + t;
    float* dst = fb + (size_t)row*64 + co0;
    #pragma unroll
    for (int m = 0; m < 4; ++m){
      float4 b0 = *reinterpret_cast<const float4*>(dst + m*4);
      float4 v;
      v.x = b0.x + acc[s][m*4+0]; v.x = v.x > 0.f ? v.x : 0.f;
      v.y = b0.y + acc[s][m*4+1]; v.y = v.y > 0.f ? v.y : 0.f;
      v.z = b0.z + acc[s][m*4+2]; v.z = v.z > 0.f ? v.z : 0.f;
      v.w = b0.w + acc[s][m*4+3]; v.w = v.w > 0.f ? v.w : 0.f;
      *reinterpret_cast<float4*>(dst + m*4) = v;
    }
  }
}

__global__ __launch_bounds__(256)
void cmba_kernel(const int* __restrict__ nbr, const uint* __restrict__ choff,
                 const float* __restrict__ slab, float* __restrict__ t0)
{
  __shared__ uint wc[4][4];
  int cb = blockIdx.x;
  int t = threadIdx.x, w = t >> 6, l = t & 63;
  float acc[4][16];
  #pragma unroll
  for (int s = 0; s < 4; ++s)
    #pragma unroll
    for (int j = 0; j < 16; ++j) acc[s][j] = 0.f;

  for (int k = 0; k < 27; ++k){
    unsigned long long bal[4];
    for (int s = 0; s < 4; ++s){
      int row = cb*1024 + s*256 + t;
      int idx = nbr[(size_t)k*NOUTC + row];
      bool f = (idx != NOUTC) && !is_sib(row & 7, k);
      bal[s] = __ballot(f);
      if (l == 0) wc[s][w] = (uint)__popcll(bal[s]);
    }
    __syncthreads();
    uint sbs[4];
    { uint r = 0; for (int s = 0; s < 4; ++s){ sbs[s] = r; for (int w2 = 0; w2 < 4; ++w2) r += wc[s][w2]; } }
    uint base = choff[k*NCH + cb];
    for (int s = 0; s < 4; ++s){
      if ((bal[s] >> l) & 1ull){
        uint off = sbs[s];
        for (int w2 = 0; w2 < w; ++w2) off += wc[s][w2];
        off += (uint)__popcll(bal[s] & ((1ull << l) - 1ull));
        uint pos = base + off;
        if (pos < CAP){
          const float4* sr = reinterpret_cast<const float4*>(slab + (size_t)pos*16);
          float4 a0 = sr[0], a1 = sr[1], a2 = sr[2], a3 = sr[3];
          acc[s][0]+=a0.x; acc[s][1]+=a0.y; acc[s][2]+=a0.z; acc[s][3]+=a0.w;
          acc[s][4]+=a1.x; acc[s][5]+=a1.y; acc[s][6]+=a1.z; acc[s][7]+=a1.w;
          acc[s][8]+=a2.x; acc[s][9]+=a2.y; acc[s][10]+=a2.z; acc[s][11]+=a2.w;
          acc[s][12]+=a3.x; acc[s][13]+=a3.y; acc[s][14]+=a3.z; acc[s][15]+=a3.w;
        }
      }
    }
    __syncthreads();
  }
  for (int s = 0; s < 4; ++s){
    int row = cb*1024 + s*256 + t;
    float* dst = t0 + (size_t)row*16;
    #pragma unroll
    for (int m = 0; m < 4; ++m){
      float4 b0 = *reinterpret_cast<const float4*>(dst + m*4);
      float4 v;
      v.x = b0.x + acc[s][m*4+0]; v.x = v.x > 0.f ? v.x : 0.f;
      v.y = b0.y + acc[s][m*4+1]; v.y = v.y > 0.f ? v.y : 0.f;
      v.z = b0.z + acc[s][m*4+2]; v.z = v.z > 0.f ? v.z : 0.f;
      v.w = b0.w + acc[s][m*4+3]; v.w = v.w > 0.f ? v.w : 0.f;
      *reinterpret_cast<float4*>(dst + m*4) = v;
    }
  }
}

// ---------------------------------------------------------------------------
// R2-proven spconv2 (used for W01, W11, W12)
// ---------------------------------------------------------------------------
template<int ROWS, int CIN, int COUT, int SPLIT, int THREADS, int NK,
         bool IDENT, bool RELU, bool RESID>
__global__ __launch_bounds__(THREADS)
void spconv2(const float* __restrict__ feats, const int* __restrict__ nbr,
             const float* __restrict__ Wg, const float* __restrict__ bias,
             const float* __restrict__ resid, float* __restrict__ outp,
             int ostride, int coff)
{
  constexpr int RG = ROWS / 8, CG = COUT / 8;
  static_assert(RG * CG * SPLIT == THREADS, "bad thread tiling");
  constexpr int CIPT = CIN / SPLIT;
  constexpr int STR  = ROWS + 4;
  constexpr int WSTR = COUT + 4;
  constexpr int TPR  = THREADS / ROWS;
  constexpr int FSTG = CIN / TPR;
  constexpr int WSTG = (CIN * COUT) / THREADS;
  constexpr int NSLOT = THREADS / SPLIT;

  constexpr int MAIN_FL = CIN * STR + CIN * WSTR;
  constexpr int RED_FL  = (SPLIT > 1) ? (THREADS / 2) * 64 : 0;
  constexpr int LDS_FL  = MAIN_FL > RED_FL ? MAIN_FL : RED_FL;
  __shared__ float smem[LDS_FL];
  float* ft = smem;
  float* Wl = smem + CIN * STR;

  const int t    = threadIdx.x;
  const int base = blockIdx.x * ROWS;
  const int sp   = t % SPLIT;
  const int slot = t / SPLIT;
  const int rg = slot / CG, cg = slot % CG;
  const int trr = rg * 8, tcc = cg * 8;
  const int gr = t / TPR, part = t % TPR;

  float4 fstg[FSTG / 4];
  alignas(16) float wstg[WSTG];
  float acc[8][8];
  #pragma unroll
  for (int a = 0; a < 8; ++a)
    #pragma unroll
    for (int b = 0; b < 8; ++b) acc[a][b] = 0.f;

  auto load_f = [&](int k) {
    int gidx = IDENT ? (base + gr) : nbr[(size_t)k * NOUTC + base + gr];
    const float4* src = reinterpret_cast<const float4*>(feats + (size_t)gidx * CIN + part * FSTG);
    #pragma unroll
    for (int j = 0; j < FSTG / 4; ++j) fstg[j] = src[j];
  };
  auto load_w = [&](int k) {
    const float* wsrc = Wg + (size_t)k * CIN * COUT + t * WSTG;
    if constexpr (WSTG % 4 == 0) {
      #pragma unroll
      for (int m = 0; m < WSTG / 4; ++m)
        *reinterpret_cast<float4*>(&wstg[4 * m]) = reinterpret_cast<const float4*>(wsrc)[m];
    } else {
      *reinterpret_cast<float2*>(&wstg[0]) = *reinterpret_cast<const float2*>(wsrc);
    }
  };

  load_f(0); load_w(0);

  for (int k = 0; k < NK; ++k) {
    #pragma unroll
    for (int j = 0; j < FSTG / 4; ++j) {
      int ci = part * FSTG + 4 * j;
      ft[(ci + 0) * STR + gr] = fstg[j].x;
      ft[(ci + 1) * STR + gr] = fstg[j].y;
      ft[(ci + 2) * STR + gr] = fstg[j].z;
      ft[(ci + 3) * STR + gr] = fstg[j].w;
    }
    #pragma unroll
    for (int m = 0; m < WSTG; ++m) {
      int widx = t * WSTG + m;
      Wl[(widx / COUT) * WSTR + (widx % COUT)] = wstg[m];
    }
    __syncthreads();
    if (k + 1 < NK) { load_f(k + 1); load_w(k + 1); }
    #pragma unroll 4
    for (int i = 0; i < CIPT; ++i) {
      int ci = sp + SPLIT * i;
      float4 f0 = *reinterpret_cast<const float4*>(&ft[ci * STR + trr]);
      float4 f1 = *reinterpret_cast<const float4*>(&ft[ci * STR + trr + 4]);
      float4 w0 = *reinterpret_cast<const float4*>(&Wl[ci * WSTR + tcc]);
      float4 w1 = *reinterpret_cast<const float4*>(&Wl[ci * WSTR + tcc + 4]);
      float fv[8] = {f0.x, f0.y, f0.z, f0.w, f1.x, f1.y, f1.z, f1.w};
      float wv[8] = {w0.x, w0.y, w0.z, w0.w, w1.x, w1.y, w1.z, w1.w};
      #pragma unroll
      for (int a = 0; a < 8; ++a)
        #pragma unroll
        for (int b = 0; b < 8; ++b)
          acc[a][b] = fmaf(fv[a], wv[b], acc[a][b]);
    }
    __syncthreads();
  }

  if constexpr (SPLIT > 1) {
    float* red = smem;
    for (int off = SPLIT / 2; off >= 1; off >>= 1) {
      __syncthreads();
      if (sp >= off && sp < 2 * off) {
        float* dst = red + ((size_t)((sp - off) * NSLOT + slot)) * 64;
        #pragma unroll
        for (int a = 0; a < 8; ++a) {
          float4 v0 = {acc[a][0], acc[a][1], acc[a][2], acc[a][3]};
          float4 v1 = {acc[a][4], acc[a][5], acc[a][6], acc[a][7]};
          *reinterpret_cast<float4*>(dst + a * 8)     = v0;
          *reinterpret_cast<float4*>(dst + a * 8 + 4) = v1;
        }
      }
      __syncthreads();
      if (sp < off) {
        const float* s = red + ((size_t)(sp * NSLOT + slot)) * 64;
        #pragma unroll
        for (int a = 0; a < 8; ++a) {
          float4 v0 = *reinterpret_cast<const float4*>(s + a * 8);
          float4 v1 = *reinterpret_cast<const float4*>(s + a * 8 + 4);
          acc[a][0] += v0.x; acc[a][1] += v0.y; acc[a][2] += v0.z; acc[a][3] += v0.w;
          acc[a][4] += v1.x; acc[a][5] += v1.y; acc[a][6] += v1.z; acc[a][7] += v1.w;
        }
      }
    }
  }

  if (sp == 0) {
    #pragma unroll
    for (int a = 0; a < 8; ++a) {
      int r = base + trr + a;
      float o[8];
      #pragma unroll
      for (int b = 0; b < 8; ++b) {
        float v = acc[a][b] + bias[tcc + b];
        if (RELU) v = v > 0.f ? v : 0.f;
        o[b] = v;
      }
      if (RESID) {
        const float* rs = resid + (size_t)r * 64 + coff + tcc;
        float4 r0 = *reinterpret_cast<const float4*>(rs);
        float4 r1 = *reinterpret_cast<const float4*>(rs + 4);
        o[0] += r0.x; o[1] += r0.y; o[2] += r0.z; o[3] += r0.w;
        o[4] += r1.x; o[5] += r1.y; o[6] += r1.z; o[7] += r1.w;
      }
      float* dst = outp + (size_t)r * ostride + coff + tcc;
      float4 s0 = {o[0], o[1], o[2], o[3]};
      float4 s1 = {o[4], o[5], o[6], o[7]};
      *reinterpret_cast<float4*>(dst)     = s0;
      *reinterpret_cast<float4*>(dst + 4) = s1;
    }
  }
}

// ---------------------------------------------------------------------------
// upsample (R2)
// ---------------------------------------------------------------------------
__global__ __launch_bounds__(256)
void upsample_kernel(const float* __restrict__ x, const float* __restrict__ Wup,
                     const float* __restrict__ bup, float* __restrict__ outp)
{
  __shared__ float Wl[64 * 64];
  __shared__ float xt[64][68];
  const int t    = threadIdx.x;
  const int tile = blockIdx.x >> 3;
  const int k    = blockIdx.x & 7;
  const int base = tile * 64;

  #pragma unroll
  for (int i = t; i < 4096; i += 256) Wl[i] = Wup[k * 4096 + i];
  {
    const int gr = t >> 2, gp = t & 3;
    const float4* src = reinterpret_cast<const float4*>(x + (size_t)(base + gr) * 64) + gp * 4;
    #pragma unroll
    for (int j = 0; j < 4; ++j) {
      float4 v = src[j];
      int ci = (gp * 4 + j) * 4;
      xt[ci + 0][gr] = v.x; xt[ci + 1][gr] = v.y;
      xt[ci + 2][gr] = v.z; xt[ci + 3][gr] = v.w;
    }
  }
  __syncthreads();
  const int tcc = (t % 16) * 4, trr = (t / 16) * 4;
  float acc[4][4];
  #pragma unroll
  for (int a = 0; a < 4; ++a)
    #pragma unroll
    for (int b = 0; b < 4; ++b) acc[a][b] = 0.f;
  #pragma unroll
  for (int ci = 0; ci < 64; ++ci) {
    float4 f = *reinterpret_cast<const float4*>(&xt[ci][trr]);
    float4 w = *reinterpret_cast<const float4*>(&Wl[ci * 64 + tcc]);
    float fv[4] = {f.x, f.y, f.z, f.w};
    float wv[4] = {w.x, w.y, w.z, w.w};
    #pragma unroll
    for (int a = 0; a < 4; ++a)
      #pragma unroll
      for (int b = 0; b < 4; ++b) acc[a][b] = fmaf(fv[a], wv[b], acc[a][b]);
  }
  #pragma unroll
  for (int a = 0; a < 4; ++a) {
    int n = base + trr + a;
    float4 o;
    float v0 = acc[a][0] + bup[tcc + 0]; o.x = v0 > 0.f ? v0 : 0.f;
    float v1 = acc[a][1] + bup[tcc + 1]; o.y = v1 > 0.f ? v1 : 0.f;
    float v2 = acc[a][2] + bup[tcc + 2]; o.z = v2 > 0.f ? v2 : 0.f;
    float v3 = acc[a][3] + bup[tcc + 3]; o.w = v3 > 0.f ? v3 : 0.f;
    *reinterpret_cast<float4*>(outp + ((size_t)n * 8 + k) * 64 + tcc) = o;
  }
}

// ---------------------------------------------------------------------------
// cls / init / detect / topk / prune (unchanged)
// ---------------------------------------------------------------------------
__global__ __launch_bounds__(256)
void cls1_kernel(const float* __restrict__ feats, const float* __restrict__ Wcls,
                 float* __restrict__ g)
{
  const int n = blockIdx.x * 256 + threadIdx.x;
  if (blockIdx.x == 0 && threadIdx.x < 28) g[(size_t)NOUTC * 28 + threadIdx.x] = 0.f;
  const float4* src = reinterpret_cast<const float4*>(feats + (size_t)n * 64);
  float f[64];
  #pragma unroll
  for (int j = 0; j < 16; ++j) {
    float4 a = src[j];
    f[4*j+0]=a.x; f[4*j+1]=a.y; f[4*j+2]=a.z; f[4*j+3]=a.w;
  }
  #pragma unroll 1
  for (int k = 0; k < 27; ++k) {
    const float* w = Wcls + k * 64;
    float s0 = 0.f, s1 = 0.f, s2 = 0.f, s3 = 0.f;
    #pragma unroll
    for (int j = 0; j < 16; ++j) {
      s0 = fmaf(f[j],      w[j],      s0);
      s1 = fmaf(f[16 + j], w[16 + j], s1);
      s2 = fmaf(f[32 + j], w[32 + j], s2);
      s3 = fmaf(f[48 + j], w[48 + j], s3);
    }
    g[(size_t)n * 28 + k] = (s0 + s1) + (s2 + s3);
  }
}

__global__ __launch_bounds__(256)
void cls2_kernel(const float* __restrict__ g, const int* __restrict__ nbr,
                 const float* __restrict__ bcls, float* __restrict__ out_cls)
{
  const int n = blockIdx.x * 256 + threadIdx.x;
  float s = bcls[0];
  #pragma unroll 1
  for (int k = 0; k < 27; ++k) {
    int idx = nbr[(size_t)k * NOUTC + n];
    s += g[(size_t)idx * 28 + k];
  }
  out_cls[n] = s;
}

__global__ void init_kernel(uint* hist1, uint* hist2, int* tie_cnt, int* flag,
                            float* fa, float* fb, float* t0, float* t1)
{
  int i = blockIdx.x * 256 + threadIdx.x;
  if (i < 65536) hist1[i] = 0;
  else if (i < 131072) hist2[i - 65536] = 0;
  if (i == 0) { tie_cnt[0] = 0; flag[0] = 0; }
  if (i < 64) { fa[(size_t)NOUTC * 64 + i] = 0.f; fb[(size_t)NOUTC * 64 + i] = 0.f; }
  if (i < 16) { t0[(size_t)NOUTC * 16 + i] = 0.f; t1[(size_t)NOUTC * 16 + i] = 0.f; }
}

__global__ void detect_kernel(const unsigned char* __restrict__ mt, int* flag)
{
  int i = blockIdx.x * 256 + threadIdx.x;
  int p = i * 4 + 1;
  if (p < NOUTC && mt[p] != 0) flag[0] = 1;
}

__global__ void hist1_kernel(const float* __restrict__ cls, uint* __restrict__ hist)
{
  for (int i = blockIdx.x * blockDim.x + threadIdx.x; i < NOUTC; i += gridDim.x * blockDim.x)
    atomicAdd(&hist[fkey(cls[i]) >> 16], 1u);
}

__global__ void scan1_kernel(const uint* __restrict__ hist, const int* __restrict__ nums,
                             uint* __restrict__ res)
{
  __shared__ uint chunk[256];
  const int t = threadIdx.x;
  uint s = 0;
  for (int j = 0; j < 256; ++j) s += hist[t * 256 + j];
  chunk[t] = s;
  __syncthreads();
  if (t == 0) {
    uint k = (uint)nums[0];
    uint cum = 0; int c = 255;
    for (; c > 0; --c) { if (cum + chunk[c] >= k) break; cum += chunk[c]; }
    int B = c * 256; uint cum2 = cum;
    for (int b = c * 256 + 255; b >= c * 256; --b) {
      if (cum2 + hist[b] >= k) { B = b; break; }
      cum2 += hist[b];
    }
    res[0] = (uint)B; res[1] = cum2;
  }
}

__global__ void hist2_kernel(const float* __restrict__ cls, const uint* __restrict__ res1,
                             uint* __restrict__ hist)
{
  const uint B = res1[0];
  for (int i = blockIdx.x * blockDim.x + threadIdx.x; i < NOUTC; i += gridDim.x * blockDim.x) {
    uint key = fkey(cls[i]);
    if ((key >> 16) == B) atomicAdd(&hist[key & 0xffffu], 1u);
  }
}

__global__ void scan2_kernel(const uint* __restrict__ hist, const uint* __restrict__ res1,
                             const int* __restrict__ nums, uint* __restrict__ res2)
{
  __shared__ uint chunk[256];
  const int t = threadIdx.x;
  uint s = 0;
  for (int j = 0; j < 256; ++j) s += hist[t * 256 + j];
  chunk[t] = s;
  __syncthreads();
  if (t == 0) {
    uint k = (uint)nums[0];
    uint cum = res1[1]; int c = 255;
    for (; c > 0; --c) { if (cum + chunk[c] >= k) break; cum += chunk[c]; }
    int L = c * 256; uint cum2 = cum;
    for (int b = c * 256 + 255; b >= c * 256; --b) {
      if (cum2 + hist[b] >= k) { L = b; break; }
      cum2 += hist[b];
    }
    res2[0] = (res1[0] << 16) | (uint)L;
    res2[1] = k - cum2;
  }
}

__global__ void mark_kernel(const float* __restrict__ cls, const uint* __restrict__ res2,
                            unsigned char* __restrict__ msel, int* tie_cnt, int* tie_idx)
{
  const uint T = res2[0];
  for (int i = blockIdx.x * blockDim.x + threadIdx.x; i < NOUTC; i += gridDim.x * blockDim.x) {
    uint key = fkey(cls[i]);
    msel[i] = key > T ? 1 : 0;
    if (key == T) {
      int p = atomicAdd(tie_cnt, 1);
      if (p < 4096) tie_idx[p] = i;
    }
  }
}

__global__ void tie_kernel(const uint* __restrict__ res2, const int* __restrict__ tie_cnt,
                           const int* __restrict__ tie_idx, unsigned char* __restrict__ msel)
{
  int need = (int)res2[1];
  int cnt = tie_cnt[0]; if (cnt > 4096) cnt = 4096;
  if (need <= 0) return;
  if (cnt <= need) {
    for (int i = threadIdx.x; i < cnt; i += 256) msel[tie_idx[i]] = 1;
  } else {
    for (int i = threadIdx.x; i < cnt; i += 256) {
      int my = tie_idx[i];
      int rank = 0;
      for (int j = 0; j < cnt; ++j) rank += (tie_idx[j] < my) ? 1 : 0;
      if (rank < need) msel[my] = 1;
    }
  }
}

__global__ void prune_kernel(const float* __restrict__ feats, const unsigned char* __restrict__ msel,
                             const void* __restrict__ mtrue, const int* __restrict__ flag,
                             float* __restrict__ dout)
{
  const unsigned char* mb = (const unsigned char*)mtrue;
  const int* mi = (const int*)mtrue;
  const bool bytes = (flag[0] != 0);
  float* pruned = dout + NOUTC;
  float* maskf  = dout + NOUTC + (size_t)NOUTC * 64;
  const float4* src = reinterpret_cast<const float4*>(feats);
  float4* dst = reinterpret_cast<float4*>(pruned);
  const int total = NOUTC * 16;
  for (int i = blockIdx.x * blockDim.x + threadIdx.x; i < total; i += gridDim.x * blockDim.x) {
    int n = i >> 4;
    bool mt = bytes ? (mb[n] != 0) : (mi[n] != 0);
    bool m = (msel[n] != 0) || mt;
    float4 v = src[i];
    float4 z = {0.f, 0.f, 0.f, 0.f};
    dst[i] = m ? v : z;
    if ((i & 15) == 0) maskf[n] = m ? 1.f : 0.f;
  }
}

// ---------------------------------------------------------------------------
extern "C" void kernel_launch(void* const* d_in, const int* in_sizes, int n_in,
                              void* d_out, int out_size, void* d_ws, size_t ws_size,
                              hipStream_t stream)
{
  const float* x    = (const float*)d_in[0];
  const float* Wup  = (const float*)d_in[1];
  const float* bup  = (const float*)d_in[2];
  const float* Wc0  = (const float*)d_in[3];
  const float* bc0  = (const float*)d_in[4];
  const float* W00  = (const float*)d_in[5];
  const float* b00  = (const float*)d_in[6];
  const float* W01  = (const float*)d_in[7];
  const float* b01  = (const float*)d_in[8];
  const float* W10  = (const float*)d_in[9];
  const float* b10  = (const float*)d_in[10];
  const float* W11  = (const float*)d_in[11];
  const float* b11  = (const float*)d_in[12];
  const float* W12  = (const float*)d_in[13];
  const float* b12  = (const float*)d_in[14];
  const float* Wcls = (const float*)d_in[15];
  const float* bcls = (const float*)d_in[16];
  const int*   nbr  = (const int*)d_in[17];
  const void*  mtrue= d_in[18];
  const int*   nums = (const int*)d_in[19];

  float* dout = (float*)d_out;

  float* fa   = (float*)d_ws;                               // (N+1)*64
  float* t0   = fa + (size_t)(NOUTC + 1) * 64;              // (N+1)*16
  float* t1   = t0 + (size_t)(NOUTC + 1) * 16;              // (N+1)*16
  float* g    = t0;                                         // cls overlay (dead by then)
  float* slab = t1 + (size_t)(NOUTC + 1) * 16;              // CAP*32 floats
  uint*  hist1 = (uint*)(slab + (size_t)CAP * 32);
  uint*  hist2 = hist1 + 65536;
  uint*  res1  = hist2 + 65536;
  uint*  res2  = res1 + 2;
  int*   tie_cnt = (int*)(res2 + 2);
  int*   flag    = tie_cnt + 1;
  int*   tie_idx = flag + 1;                                // 4096
  uint*  counts  = (uint*)(tie_idx + 4096);                 // 3456
  uint*  choff   = counts + 27 * NCH;                       // 3456
  int*   karr    = (int*)(choff + 27 * NCH);                // MAXB
  int*   meta    = karr + MAXB;                             // pad
  uint2* entries = (uint2*)(meta + 4);                      // CAP
  unsigned char* msel = (unsigned char*)(entries + CAP);    // NOUTC bytes
  float* WW   = (float*)(msel + NOUTC);                     // 262144 floats
  float* WW2  = WW + 262144;                                // 3 * 131072 floats
  float* fb = dout + NOUTC;   // (N+1)*64 parked in d_out's pruned+mask region

  init_kernel<<<512, 256, 0, stream>>>(hist1, hist2, tie_cnt, flag, fa, fb, t0, t1);
  detect_kernel<<<128, 256, 0, stream>>>((const unsigned char*)mtrue, flag);

  // build sparse-entry lists + expanded sib weight matrices
  hipMemsetAsync(entries, 0xFF, (size_t)CAP * sizeof(uint2), stream);
  count_kernel<<<27 * NCH, 256, 0, stream>>>(nbr, counts);
  scan_kernel<<<1, 256, 0, stream>>>(counts, choff, karr);
  fill_kernel<<<27 * NCH, 256, 0, stream>>>(nbr, choff, entries);
  ww_prep_c0<<<1024, 256, 0, stream>>>(Wc0, WW);
  for (int i = 0; i < 3; ++i)
    ww_prep_a2<<<512, 256, 0, stream>>>(W00 + (size_t)i * 27 * 1024,
                                        W10 + (size_t)i * 1024,
                                        WW2 + (size_t)i * 131072);

  upsample_kernel<<<2048, 256, 0, stream>>>(x, Wup, bup, fa);

  // c0 = relu(sibGEMM + sparse + bc0)
  gemm_ww3<63, false><<<512, 256, 0, stream>>>(fa, WW, bc0, nullptr, fb, nullptr, 512);
  p1c0_kernel<<<MAXB, 128, 0, stream>>>(fa, Wc0, entries, karr, slab, 0);
  cmbc0_kernel<<<256, 256, 0, stream>>>(nbr, choff, slab, fb, 0);
  p1c0_kernel<<<MAXB, 128, 0, stream>>>(fa, Wc0, entries, karr, slab, 1);
  cmbc0_kernel<<<256, 256, 0, stream>>>(nbr, choff, slab, fb, 1);

  const float* cur = fb; float* nxt = fa;
  for (int i = 0; i < 3; ++i) {
    const float* W00i = W00 + (size_t)i * 27 * 1024;
    // t0 = sibGEMM(W00)+b00 (pre-sparse), t1 = relu(cur@W10+b10) — one GEMM
    gemm_ww3<15, true><<<256, 256, 0, stream>>>(cur, WW2 + (size_t)i * 131072,
                                                b00 + i * 16, b10 + i * 16,
                                                t0, t1, 256);
    p1a_kernel<<<MAXB, 128, 0, stream>>>(cur, W00i, entries, karr, slab);
    cmba_kernel<<<128, 256, 0, stream>>>(nbr, choff, slab, t0);
    // nxt[:,0:32] = spconv(t0, W01) + b01 + cur[:,0:32]
    spconv2<128, 16, 32, 4, 256, 27, false, false, true>
        <<<NOUTC / 128, 256, 0, stream>>>(t0, nbr, W01 + (size_t)i * 27 * 512,
                                          b01 + i * 32, cur, nxt, 64, 0);
    // t0 = relu(spconv(t1, W11) + b11)
    spconv2<128, 16, 16, 4, 128, 27, false, true, false>
        <<<NOUTC / 128, 128, 0, stream>>>(t1, nbr, W11 + (size_t)i * 27 * 256,
                                          b11 + i * 16, nullptr, t0, 16, 0);
    // nxt[:,32:64] = t0 @ W12 + b12 + cur[:,32:64]
    spconv2<128, 16, 32, 4, 256, 1, true, false, true>
        <<<NOUTC / 128, 256, 0, stream>>>(t0, nullptr, W12 + (size_t)i * 512,
                                          b12 + i * 32, cur, nxt, 64, 32);
    float* tmp = (float*)cur; cur = nxt; nxt = tmp;
  }
  // final features in fa

  cls1_kernel<<<512, 256, 0, stream>>>(cur, Wcls, g);
  cls2_kernel<<<512, 256, 0, stream>>>(g, nbr, bcls, dout);

  hist1_kernel<<<512, 256, 0, stream>>>(dout, hist1);
  scan1_kernel<<<1, 256, 0, stream>>>(hist1, nums, res1);
  hist2_kernel<<<512, 256, 0, stream>>>(dout, res1, hist2);
  scan2_kernel<<<1, 256, 0, stream>>>(hist2, res1, nums, res2);
  mark_kernel<<<512, 256, 0, stream>>>(dout, res2, msel, tie_cnt, tie_idx);
  tie_kernel<<<1, 256, 0, stream>>>(res2, tie_cnt, tie_idx, msel);
  prune_kernel<<<4096, 256, 0, stream>>>(cur, msel, mtrue, flag, dout);
}